// Round 13
// baseline (140.352 us; speedup 1.0000x reference)
//
#include <hip/hip_runtime.h>

#define B_   1024
#define L_   2048
#define IND_ 64
#define H_   4
#define K_   64

// monotone float->uint key (order-preserving), and inverse
__device__ __forceinline__ unsigned f2key(float s) {
  unsigned u = __float_as_uint(s);
  return (u & 0x80000000u) ? ~u : (u | 0x80000000u);
}
__device__ __forceinline__ float key2f(unsigned k) {
  unsigned u = (k & 0x80000000u) ? (k & 0x7FFFFFFFu) : ~k;
  return __uint_as_float(u);
}

// DPP cross-lane move (bound_ctrl=true: invalid -> 0).
// quad_perm 0xB1 = [1,0,3,2] (xor 1); 0x4E = [2,3,0,1] (xor 2).
template <int CTRL>
__device__ __forceinline__ float dpp_f(float x) {
  return __int_as_float(
      __builtin_amdgcn_update_dpp(0, __float_as_int(x), CTRL, 0xf, 0xf, true));
}
// ds_swizzle BitMode xor: offset = (xor<<10) | 0x1F. LDS pipe (offloads VALU).
template <int OFF>
__device__ __forceinline__ float swz_f(float x) {
  return __int_as_float(__builtin_amdgcn_ds_swizzle(__float_as_int(x), OFF));
}

// ---------------- ONE fused kernel: one block per b; 4 waves ----------------
// prep (wave 0, double, bitwise-identical order to the old prep_weff) ->
// phase-1 streaming (R11/R12 verified: wave-interleaved, 8-deep pipelined,
// butterfly reduce) -> selection (binary search, row-ordered compaction) ->
// gather -> epilogue via (svec@Wv_h)@Wo_h  [M never materialized].
__global__ __launch_bounds__(256, 4) void attn_all_k(const float* __restrict__ target,
                                                     const float* __restrict__ seq,
                                                     const int* __restrict__ mask,
                                                     const float* __restrict__ Wq,
                                                     const float* __restrict__ Wh,
                                                     const float* __restrict__ Wv,
                                                     const float* __restrict__ Wo,
                                                     float* __restrict__ out) {
  __shared__ float  scores[L_ * H_];  // 32 KB, layout [row][h]
  __shared__ float  tgt[64];
  __shared__ double qd[64];
  __shared__ float  weff_s[H_ * 64];  // [h][i]
  __shared__ int    sidx[H_][K_];
  __shared__ float  sw[H_][K_];
  __shared__ float  svec[H_][64];
  __shared__ float  tvec[H_][16];
  __shared__ float  part[H_][64];

  const int b = blockIdx.x;
  const int tid = threadIdx.x;
  const int w = tid >> 6;   // wave id (phase1: interleave slot; later: head id)
  const int ln = tid & 63;
  const int g = ln >> 4;    // row subgroup 0..3
  const int j = ln & 15;    // float4 column index
  const float* __restrict__ seqb = seq + (size_t)b * (L_ * IND_);
  const int* __restrict__ maskb = mask + (size_t)b * L_;
  const bool b1 = (ln & 1) != 0;
  const bool b2 = (ln & 2) != 0;

  // ---- mask loads issued first; they complete under the prep below ----
  unsigned mbits = 0;
#pragma unroll
  for (int t = 0; t < 32; ++t) mbits |= (maskb[(t << 6) + ln] ? 1u : 0u) << t;

  // ---- fused prep: wave 0 computes weff in double (same op order as the
  // ---- old prep_weff kernel -> bitwise-identical scores -> same top-k) ----
  if (tid < 64) tgt[tid] = target[b * 64 + tid];
  __syncthreads();
  if (tid < 64) {
    double acc = 0.0;
#pragma unroll
    for (int jj = 0; jj < 64; ++jj)
      acc += (double)tgt[jj] * (double)Wq[jj * 64 + tid];
    qd[tid] = acc;
  }
  __syncthreads();
  if (tid < 64) {
#pragma unroll
    for (int h = 0; h < H_; ++h) {
      double a2 = 0.0;
#pragma unroll
      for (int d = 0; d < 16; ++d)
        a2 += qd[h * 16 + d] * (double)Wh[tid * 64 + h * 16 + d];
      weff_s[h * 64 + tid] = (float)(a2 * 0.25);  // fold 1/SCALE
    }
  }
  __syncthreads();

  // per-lane wef fragment from LDS: wefv[h][e] = weff[h][4j+e]
  float wefv[H_][4];
#pragma unroll
  for (int h = 0; h < H_; ++h) {
#pragma unroll
    for (int e = 0; e < 4; ++e) wefv[h][e] = weff_s[h * 64 + (j << 2) + e];
  }

  // ---------- phase 1: wave-interleaved streaming, 8-deep pipeline ----------
  // row = s*16 + w*4 + g, col = j  ->  float4 idx = s*256 + w*64 + g*16 + j
  const float4* __restrict__ lp4 =
      reinterpret_cast<const float4*>(seqb) + (w << 6) + (g << 4) + j;
  const int rb0 = (w << 2) + g;  // row base (without s*16 term)

  float4 vvA[8], vvB[8];

#define LOADB(V, SB)                                                          \
  {                                                                           \
    _Pragma("unroll") for (int u = 0; u < 8; ++u)                             \
        V[u] = lp4[(((SB) << 3) + u) << 8];                                   \
  }
#define COMPUTE(V, SB)                                                        \
  {                                                                           \
    _Pragma("unroll") for (int u = 0; u < 8; ++u) {                           \
      const int s = ((SB) << 3) + u;                                          \
      const float4 v = V[u];                                                  \
      float p0 = v.x * wefv[0][0]; p0 = fmaf(v.y, wefv[0][1], p0);            \
      p0 = fmaf(v.z, wefv[0][2], p0); p0 = fmaf(v.w, wefv[0][3], p0);         \
      float p1 = v.x * wefv[1][0]; p1 = fmaf(v.y, wefv[1][1], p1);            \
      p1 = fmaf(v.z, wefv[1][2], p1); p1 = fmaf(v.w, wefv[1][3], p1);         \
      float p2 = v.x * wefv[2][0]; p2 = fmaf(v.y, wefv[2][1], p2);            \
      p2 = fmaf(v.z, wefv[2][2], p2); p2 = fmaf(v.w, wefv[2][3], p2);         \
      float p3 = v.x * wefv[3][0]; p3 = fmaf(v.y, wefv[3][1], p3);            \
      p3 = fmaf(v.z, wefv[3][2], p3); p3 = fmaf(v.w, wefv[3][3], p3);         \
      /* head-interleaved butterfly over the 16-lane group */                 \
      const float a  = (b1 ? p1 : p0) + dpp_f<0xB1>(b1 ? p0 : p1);            \
      const float bb = (b1 ? p3 : p2) + dpp_f<0xB1>(b1 ? p2 : p3);            \
      float c = (b2 ? bb : a) + dpp_f<0x4E>(b2 ? a : bb);                     \
      c += swz_f<0x101F>(c); /* xor 4 */                                      \
      c += swz_f<0x201F>(c); /* xor 8 */                                      \
      const int row = (s << 4) + rb0;                                         \
      if (j < 4) scores[(row << 2) + j] = c;                                  \
    }                                                                         \
  }

  LOADB(vvA, 0);
  LOADB(vvB, 1);  COMPUTE(vvA, 0);
  LOADB(vvA, 2);  COMPUTE(vvB, 1);
  LOADB(vvB, 3);  COMPUTE(vvA, 2);
  LOADB(vvA, 4);  COMPUTE(vvB, 3);
  LOADB(vvB, 5);  COMPUTE(vvA, 4);
  LOADB(vvA, 6);  COMPUTE(vvB, 5);
  LOADB(vvB, 7);  COMPUTE(vvA, 6);
  LOADB(vvA, 8);  COMPUTE(vvB, 7);
  LOADB(vvB, 9);  COMPUTE(vvA, 8);
  LOADB(vvA, 10); COMPUTE(vvB, 9);
  LOADB(vvB, 11); COMPUTE(vvA, 10);
  LOADB(vvA, 12); COMPUTE(vvB, 11);
  LOADB(vvB, 13); COMPUTE(vvA, 12);
  LOADB(vvA, 14); COMPUTE(vvB, 13);
  LOADB(vvB, 15); COMPUTE(vvA, 14);
                  COMPUTE(vvB, 15);
#undef LOADB
#undef COMPUTE

  __syncthreads();  // scoreboard complete; wave w now owns head w

  // ---------- selection: exact 64th-largest via bitwise binary search ------
  unsigned kk[32];
  const unsigned KNEG = f2key(-1e9f);
#pragma unroll
  for (int t = 0; t < 32; ++t) {
    const float s_ = scores[(((t << 6) + ln) << 2) + w];
    kk[t] = ((mbits >> t) & 1u) ? f2key(s_) : KNEG;
  }

  unsigned kmax = 0u;
#pragma unroll
  for (int q = 0; q < 32; ++q) kmax = max(kmax, kk[q]);
#pragma unroll
  for (int off = 32; off >= 1; off >>= 1)
    kmax = max(kmax, (unsigned)__shfl_xor((int)kmax, off, 64));
  const float smax = key2f(kmax);

  unsigned lo = 0u, hi = 0xFFFFFFFFu;
  while (lo < hi) {  // find max t with count(key >= t) >= 64
    const unsigned span = hi - lo;
    const unsigned mid = lo + (span >> 1) + (span & 1u);
    int c = 0;
#pragma unroll
    for (int q = 0; q < 32; ++q) c += (kk[q] >= mid) ? 1 : 0;
#pragma unroll
    for (int off = 32; off >= 1; off >>= 1) c += __shfl_xor(c, off, 64);
    if (c >= K_) lo = mid; else hi = mid - 1;
  }
  const unsigned V = lo;
  int cg = 0;
#pragma unroll
  for (int q = 0; q < 32; ++q) cg += (kk[q] > V) ? 1 : 0;
#pragma unroll
  for (int off = 32; off >= 1; off >>= 1) cg += __shfl_xor(cg, off, 64);
  const int m = K_ - cg;  // #ties (==V) to take, lowest index first (lax.top_k stable)

  // row-ordered compaction (R12): sidx ascending -> monotone gather
  {
    const unsigned long long lmlt = (1ull << ln) - 1ull;
    int base = 0, etaken = 0;
#pragma unroll
    for (int q = 0; q < 32; ++q) {
      const unsigned key = kk[q];
      const int l = ln + (q << 6);  // lane order == index order within chunk
      const bool gt = key > V;
      const bool eq = key == V;
      const unsigned long long beq = __ballot(eq);
      const int rk = __popcll(beq & lmlt);         // eq rank within chunk
      const bool sel = gt || (eq && (etaken + rk) < m);
      const unsigned long long bsel = __ballot(sel);
      if (sel) {
        const int pos = base + __popcll(bsel & lmlt);
        sidx[w][pos] = l;
        sw[w][pos] = expf(key2f(key) - smax);
      }
      base += __popcll(bsel);
      etaken += min(m - etaken, __popcll(beq));
    }
  }
  // no barrier: sidx/sw written and read by the same wave

  // ---------- gather + softmax-weighted sum of raw seq rows ----------
  {
    const int cg4 = ln & 15;  // float4 column group
    const int rg = ln >> 4;   // row subgroup 0..3
    float4 sv = make_float4(0.f, 0.f, 0.f, 0.f);
    float z = 0.f;
#pragma unroll
    for (int q = 0; q < 16; ++q) {
      const int sl = (q << 2) + rg;
      const int idx = sidx[w][sl];
      const float wt = sw[w][sl];
      const float4 v =
          *reinterpret_cast<const float4*>(seqb + (size_t)idx * 64 + (cg4 << 2));
      sv.x = fmaf(wt, v.x, sv.x);
      sv.y = fmaf(wt, v.y, sv.y);
      sv.z = fmaf(wt, v.z, sv.z);
      sv.w = fmaf(wt, v.w, sv.w);
      z += wt;
    }
#pragma unroll
    for (int off = 16; off <= 32; off <<= 1) {
      sv.x += __shfl_xor(sv.x, off, 64);
      sv.y += __shfl_xor(sv.y, off, 64);
      sv.z += __shfl_xor(sv.z, off, 64);
      sv.w += __shfl_xor(sv.w, off, 64);
      z += __shfl_xor(z, off, 64);
    }
    if (rg == 0) {  // lanes 0..15 hold the reduced result
      const float inv = 1.f / z;
      svec[w][(cg4 << 2) + 0] = sv.x * inv;
      svec[w][(cg4 << 2) + 1] = sv.y * inv;
      svec[w][(cg4 << 2) + 2] = sv.z * inv;
      svec[w][(cg4 << 2) + 3] = sv.w * inv;
    }
  }
  // svec written and read by the same wave -> no barrier

  // ---------- epilogue: out_h = (svec_h @ Wv_h) @ Wo_h  (no M table) ------
  {
    // t[d] = sum_i svec[i] * Wv[i][w*16+d]; lane (g,j) does i = 4*i16+g, d=j
    float tp = 0.f;
#pragma unroll
    for (int i16 = 0; i16 < 16; ++i16) {
      const int i = (i16 << 2) + g;
      tp = fmaf(svec[w][i], Wv[i * 64 + (w << 4) + j], tp);
    }
    tp += __shfl_xor(tp, 16, 64);
    tp += __shfl_xor(tp, 32, 64);   // all lanes now hold t[d=j]
    if (ln < 16) tvec[w][ln] = tp;  // lane ln<16 has g==0, d=ln
    // o[ln] = sum_d t[d] * Wo[w*16+d][ln]   (in-wave LDS RAW, ordered)
    float o = 0.f;
#pragma unroll
    for (int d = 0; d < 16; ++d)
      o = fmaf(tvec[w][d], Wo[((w << 4) + d) * 64 + ln], o);
    part[w][ln] = o;
  }
  __syncthreads();
  if (tid < 64)
    out[(size_t)b * 64 + tid] = part[0][tid] + part[1][tid] + part[2][tid] + part[3][tid];
}

extern "C" void kernel_launch(void* const* d_in, const int* in_sizes, int n_in,
                              void* d_out, int out_size, void* d_ws, size_t ws_size,
                              hipStream_t stream) {
  const float* target = (const float*)d_in[0];
  const float* seq    = (const float*)d_in[1];
  const int*   mask   = (const int*)d_in[2];
  const float* Wq     = (const float*)d_in[3];
  const float* Wh     = (const float*)d_in[4];
  const float* Wv     = (const float*)d_in[5];
  const float* Wo     = (const float*)d_in[6];
  float* out = (float*)d_out;
  (void)d_ws; (void)ws_size;

  attn_all_k<<<B_, 256, 0, stream>>>(target, seq, mask, Wq, Wh, Wv, Wo, out);
}

// Round 14
// 124.980 us; speedup vs baseline: 1.1230x; 1.1230x over previous
//
#include <hip/hip_runtime.h>

#define B_   1024
#define L_   2048
#define IND_ 64
#define H_   4
#define K_   64

// ---------------- prep: w_eff[b][h][i] = (1/4) * sum_d q[b,h,d] * Wh[i, h*16+d]
__global__ __launch_bounds__(64) void prep_weff_k(const float* __restrict__ target,
                                                  const float* __restrict__ Wq,
                                                  const float* __restrict__ Wh,
                                                  float* __restrict__ weff) {
  const int b = blockIdx.x;
  const int t = threadIdx.x;  // 0..63
  __shared__ float tgt[64];
  __shared__ double q[64];
  tgt[t] = target[b * 64 + t];
  __syncthreads();
  double acc = 0.0;
#pragma unroll
  for (int j = 0; j < 64; ++j) acc += (double)tgt[j] * (double)Wq[j * 64 + t];
  q[t] = acc;
  __syncthreads();
#pragma unroll
  for (int h = 0; h < H_; ++h) {
    double a2 = 0.0;
#pragma unroll
    for (int d = 0; d < 16; ++d) a2 += q[h * 16 + d] * (double)Wh[t * 64 + h * 16 + d];
    weff[((size_t)b * H_ + h) * 64 + t] = (float)(a2 * 0.25);  // fold 1/SCALE
  }
}

// monotone float->uint key (order-preserving), and inverse
__device__ __forceinline__ unsigned f2key(float s) {
  unsigned u = __float_as_uint(s);
  return (u & 0x80000000u) ? ~u : (u | 0x80000000u);
}
__device__ __forceinline__ float key2f(unsigned k) {
  unsigned u = (k & 0x80000000u) ? (k & 0x7FFFFFFFu) : ~k;
  return __uint_as_float(u);
}

// DPP cross-lane move (bound_ctrl=true: invalid -> 0).
// quad_perm 0xB1 = [1,0,3,2] (xor 1); 0x4E = [2,3,0,1] (xor 2).
template <int CTRL>
__device__ __forceinline__ float dpp_f(float x) {
  return __int_as_float(
      __builtin_amdgcn_update_dpp(0, __float_as_int(x), CTRL, 0xf, 0xf, true));
}
// ds_swizzle BitMode xor: offset = (xor<<10) | 0x1F. LDS pipe (offloads VALU).
template <int OFF>
__device__ __forceinline__ float swz_f(float x) {
  return __int_as_float(__builtin_amdgcn_ds_swizzle(__float_as_int(x), OFF));
}

// ---------------- main kernel: one block per b; 4 waves (R11 structure) -----
// Phase 1: wave-interleaved streaming, 8-deep double-buffered pipelined loads,
// head-interleaved butterfly reduce. Selection: exact 64th-largest binary
// search + two-ended compaction. Gather: verified. Epilogue: R13-verified
// (svec_h @ Wv_h) @ Wo_h -- no M table, no prep_M launch.
__global__ __launch_bounds__(256, 4) void attn_main_k(const float* __restrict__ seq,
                                                      const int* __restrict__ mask,
                                                      const float* __restrict__ weff,
                                                      const float* __restrict__ Wv,
                                                      const float* __restrict__ Wo,
                                                      float* __restrict__ out) {
  __shared__ float scores[L_ * H_];  // 32 KB, layout [row][h]
  __shared__ int   sidx[H_][K_];
  __shared__ float sw[H_][K_];
  __shared__ float svec[H_][64];
  __shared__ float tvec[H_][16];
  __shared__ float part[H_][64];

  const int b = blockIdx.x;
  const int tid = threadIdx.x;
  const int w = tid >> 6;   // wave id (phase1: interleave slot; later: head id)
  const int ln = tid & 63;
  const int g = ln >> 4;    // row subgroup 0..3
  const int j = ln & 15;    // float4 column index
  const float* __restrict__ seqb = seq + (size_t)b * (L_ * IND_);
  const int* __restrict__ maskb = mask + (size_t)b * L_;
  const bool b1 = (ln & 1) != 0;
  const bool b2 = (ln & 2) != 0;

  // per-lane wef fragment: wefv[h][e] = weff[b][h][4j+e]  (16 VGPRs)
  float wefv[H_][4];
  {
    const float* wp = weff + (size_t)b * (H_ * 64) + (j << 2);
#pragma unroll
    for (int h = 0; h < H_; ++h) {
      const float4 v = *reinterpret_cast<const float4*>(wp + (h << 6));
      wefv[h][0] = v.x; wefv[h][1] = v.y; wefv[h][2] = v.z; wefv[h][3] = v.w;
    }
  }

  // ---------- phase 1: scoring, zero barriers, 8-deep pipelined batches ----
  // row = s*16 + w*4 + g, col = j  ->  float4 idx = s*256 + w*64 + g*16 + j
  const float4* __restrict__ lp4 =
      reinterpret_cast<const float4*>(seqb) + (w << 6) + (g << 4) + j;
  const int rb0 = (w << 2) + g;  // row base (without s*16 term)

  float4 vvA[8], vvB[8];

#define LOADB(V, SB)                                                          \
  {                                                                           \
    _Pragma("unroll") for (int u = 0; u < 8; ++u)                             \
        V[u] = lp4[(((SB) << 3) + u) << 8];                                   \
  }
#define COMPUTE(V, SB)                                                        \
  {                                                                           \
    _Pragma("unroll") for (int u = 0; u < 8; ++u) {                           \
      const int s = ((SB) << 3) + u;                                          \
      const float4 v = V[u];                                                  \
      float p0 = v.x * wefv[0][0]; p0 = fmaf(v.y, wefv[0][1], p0);            \
      p0 = fmaf(v.z, wefv[0][2], p0); p0 = fmaf(v.w, wefv[0][3], p0);         \
      float p1 = v.x * wefv[1][0]; p1 = fmaf(v.y, wefv[1][1], p1);            \
      p1 = fmaf(v.z, wefv[1][2], p1); p1 = fmaf(v.w, wefv[1][3], p1);         \
      float p2 = v.x * wefv[2][0]; p2 = fmaf(v.y, wefv[2][1], p2);            \
      p2 = fmaf(v.z, wefv[2][2], p2); p2 = fmaf(v.w, wefv[2][3], p2);         \
      float p3 = v.x * wefv[3][0]; p3 = fmaf(v.y, wefv[3][1], p3);            \
      p3 = fmaf(v.z, wefv[3][2], p3); p3 = fmaf(v.w, wefv[3][3], p3);         \
      /* head-interleaved butterfly over the 16-lane group */                 \
      const float a  = (b1 ? p1 : p0) + dpp_f<0xB1>(b1 ? p0 : p1);            \
      const float bb = (b1 ? p3 : p2) + dpp_f<0xB1>(b1 ? p2 : p3);            \
      float c = (b2 ? bb : a) + dpp_f<0x4E>(b2 ? a : bb);                     \
      c += swz_f<0x101F>(c); /* xor 4 */                                      \
      c += swz_f<0x201F>(c); /* xor 8 */                                      \
      const int row = (s << 4) + rb0;                                         \
      if (j < 4) scores[(row << 2) + j] = c;                                  \
    }                                                                         \
  }

  LOADB(vvA, 0);
  LOADB(vvB, 1);  COMPUTE(vvA, 0);
  LOADB(vvA, 2);  COMPUTE(vvB, 1);
  LOADB(vvB, 3);  COMPUTE(vvA, 2);
  LOADB(vvA, 4);  COMPUTE(vvB, 3);
  LOADB(vvB, 5);  COMPUTE(vvA, 4);
  LOADB(vvA, 6);  COMPUTE(vvB, 5);
  LOADB(vvB, 7);  COMPUTE(vvA, 6);
  LOADB(vvA, 8);  COMPUTE(vvB, 7);
  LOADB(vvB, 9);  COMPUTE(vvA, 8);
  LOADB(vvA, 10); COMPUTE(vvB, 9);
  LOADB(vvB, 11); COMPUTE(vvA, 10);
  LOADB(vvA, 12); COMPUTE(vvB, 11);
  LOADB(vvB, 13); COMPUTE(vvA, 12);
  LOADB(vvA, 14); COMPUTE(vvB, 13);
  LOADB(vvB, 15); COMPUTE(vvA, 14);
                  COMPUTE(vvB, 15);
#undef LOADB
#undef COMPUTE

  // mask bits for this lane's selection rows
  unsigned mbits = 0;
#pragma unroll
  for (int t = 0; t < 32; ++t) mbits |= (maskb[(t << 6) + ln] ? 1u : 0u) << t;

  __syncthreads();  // scoreboard complete; wave w now owns head w

  // ---------- selection: exact 64th-largest via bitwise binary search ------
  unsigned kk[32];
  const unsigned KNEG = f2key(-1e9f);
#pragma unroll
  for (int t = 0; t < 32; ++t) {
    const float s_ = scores[(((t << 6) + ln) << 2) + w];
    kk[t] = ((mbits >> t) & 1u) ? f2key(s_) : KNEG;
  }

  unsigned kmax = 0u;
#pragma unroll
  for (int q = 0; q < 32; ++q) kmax = max(kmax, kk[q]);
#pragma unroll
  for (int off = 32; off >= 1; off >>= 1)
    kmax = max(kmax, (unsigned)__shfl_xor((int)kmax, off, 64));
  const float smax = key2f(kmax);

  unsigned lo = 0u, hi = 0xFFFFFFFFu;
  while (lo < hi) {  // find max t with count(key >= t) >= 64
    const unsigned span = hi - lo;
    const unsigned mid = lo + (span >> 1) + (span & 1u);
    int c = 0;
#pragma unroll
    for (int q = 0; q < 32; ++q) c += (kk[q] >= mid) ? 1 : 0;
#pragma unroll
    for (int off = 32; off >= 1; off >>= 1) c += __shfl_xor(c, off, 64);
    if (c >= K_) lo = mid; else hi = mid - 1;
  }
  const unsigned V = lo;
  int cg = 0;
#pragma unroll
  for (int q = 0; q < 32; ++q) cg += (kk[q] > V) ? 1 : 0;
#pragma unroll
  for (int off = 32; off >= 1; off >>= 1) cg += __shfl_xor(cg, off, 64);
  const int m = K_ - cg;  // #ties (==V) to take, lowest index first (lax.top_k stable)

  {
    const unsigned long long lmlt = (1ull << ln) - 1ull;
    int gbase = 0, etaken = 0;
#pragma unroll
    for (int q = 0; q < 32; ++q) {
      const unsigned key = kk[q];
      const int l = ln + (q << 6);  // lane order == index order within chunk
      const bool gt = key > V;
      const bool eq = key == V;
      const unsigned long long bgt = __ballot(gt);
      const unsigned long long beq = __ballot(eq);
      if (gt) {
        const int pos = gbase + __popcll(bgt & lmlt);
        sidx[w][pos] = l;
        sw[w][pos] = expf(key2f(key) - smax);
      }
      const int navail = __popcll(beq);
      const int take = min(m - etaken, navail);
      if (eq) {
        const int rk = __popcll(beq & lmlt);
        if (rk < take) {
          const int pos = 63 - (etaken + rk);  // ties fill from the back
          sidx[w][pos] = l;
          sw[w][pos] = expf(key2f(key) - smax);
        }
      }
      gbase += __popcll(bgt);
      etaken += take;
    }
  }
  // no barrier: sidx/sw written and read by the same wave

  // ---------- gather + softmax-weighted sum of raw seq rows ----------
  {
    const int cg4 = ln & 15;  // float4 column group
    const int rg = ln >> 4;   // row subgroup 0..3
    float4 sv = make_float4(0.f, 0.f, 0.f, 0.f);
    float z = 0.f;
#pragma unroll
    for (int q = 0; q < 16; ++q) {
      const int sl = (q << 2) + rg;
      const int idx = sidx[w][sl];
      const float wt = sw[w][sl];
      const float4 v =
          *reinterpret_cast<const float4*>(seqb + (size_t)idx * 64 + (cg4 << 2));
      sv.x = fmaf(wt, v.x, sv.x);
      sv.y = fmaf(wt, v.y, sv.y);
      sv.z = fmaf(wt, v.z, sv.z);
      sv.w = fmaf(wt, v.w, sv.w);
      z += wt;
    }
#pragma unroll
    for (int off = 16; off <= 32; off <<= 1) {
      sv.x += __shfl_xor(sv.x, off, 64);
      sv.y += __shfl_xor(sv.y, off, 64);
      sv.z += __shfl_xor(sv.z, off, 64);
      sv.w += __shfl_xor(sv.w, off, 64);
      z += __shfl_xor(z, off, 64);
    }
    if (rg == 0) {  // lanes 0..15 hold the reduced result
      const float inv = 1.f / z;
      svec[w][(cg4 << 2) + 0] = sv.x * inv;
      svec[w][(cg4 << 2) + 1] = sv.y * inv;
      svec[w][(cg4 << 2) + 2] = sv.z * inv;
      svec[w][(cg4 << 2) + 3] = sv.w * inv;
    }
  }
  // svec written and read by the same wave -> no barrier

  // ---------- epilogue (R13-verified): out_h = (svec_h @ Wv_h) @ Wo_h ------
  {
    // t[d] = sum_i svec[i] * Wv[i][w*16+d]; lane (g,j) does i = 4*i16+g, d=j
    float tp = 0.f;
#pragma unroll
    for (int i16 = 0; i16 < 16; ++i16) {
      const int i = (i16 << 2) + g;
      tp = fmaf(svec[w][i], Wv[i * 64 + (w << 4) + j], tp);
    }
    tp += __shfl_xor(tp, 16, 64);
    tp += __shfl_xor(tp, 32, 64);   // all lanes now hold t[d=j]
    if (ln < 16) tvec[w][ln] = tp;  // lane ln<16 has g==0, d=ln
    float o = 0.f;
#pragma unroll
    for (int d = 0; d < 16; ++d)
      o = fmaf(tvec[w][d], Wo[((w << 4) + d) * 64 + ln], o);
    part[w][ln] = o;
  }
  __syncthreads();
  if (tid < 64)
    out[(size_t)b * 64 + tid] = part[0][tid] + part[1][tid] + part[2][tid] + part[3][tid];
}

extern "C" void kernel_launch(void* const* d_in, const int* in_sizes, int n_in,
                              void* d_out, int out_size, void* d_ws, size_t ws_size,
                              hipStream_t stream) {
  const float* target = (const float*)d_in[0];
  const float* seq    = (const float*)d_in[1];
  const int*   mask   = (const int*)d_in[2];
  const float* Wq     = (const float*)d_in[3];
  const float* Wh     = (const float*)d_in[4];
  const float* Wv     = (const float*)d_in[5];
  const float* Wo     = (const float*)d_in[6];
  float* out  = (float*)d_out;
  float* weff = (float*)d_ws;  // B*H*64 floats = 1 MB

  prep_weff_k<<<B_, 64, 0, stream>>>(target, Wq, Wh, weff);
  attn_main_k<<<B_, 256, 0, stream>>>(seq, mask, weff, Wv, Wo, out);
}

// Round 15
// 122.067 us; speedup vs baseline: 1.1498x; 1.0239x over previous
//
#include <hip/hip_runtime.h>

#define B_   1024
#define L_   2048
#define IND_ 64
#define H_   4
#define K_   64

// monotone float->uint key (order-preserving), and inverse
__device__ __forceinline__ unsigned f2key(float s) {
  unsigned u = __float_as_uint(s);
  return (u & 0x80000000u) ? ~u : (u | 0x80000000u);
}
__device__ __forceinline__ float key2f(unsigned k) {
  unsigned u = (k & 0x80000000u) ? (k & 0x7FFFFFFFu) : ~k;
  return __uint_as_float(u);
}

// DPP cross-lane move (bound_ctrl=true: invalid -> 0).
// quad_perm 0xB1 = [1,0,3,2] (xor 1); 0x4E = [2,3,0,1] (xor 2).
template <int CTRL>
__device__ __forceinline__ float dpp_f(float x) {
  return __int_as_float(
      __builtin_amdgcn_update_dpp(0, __float_as_int(x), CTRL, 0xf, 0xf, true));
}
// ds_swizzle BitMode xor: offset = (xor<<10) | 0x1F. LDS pipe (offloads VALU).
template <int OFF>
__device__ __forceinline__ float swz_f(float x) {
  return __int_as_float(__builtin_amdgcn_ds_swizzle(__float_as_int(x), OFF));
}

// ---------------- ONE kernel: one block per b; 4 waves ----------------------
// weff computed per-wave REDUNDANTLY via in-wave shuffles (f64, no barriers,
// overlapped with the pipeline-prologue loads) -- fixes R13's serialization.
// Phase 1: wave-interleaved streaming, 8-deep pipelined loads, butterfly
// reduce (R11). Selection: exact 64th-largest + two-ended compaction.
// Epilogue: (svec_h @ Wv_h) @ Wo_h  (R13/R14-verified, no M table).
__global__ __launch_bounds__(256, 4) void attn_main_k(const float* __restrict__ target,
                                                      const float* __restrict__ seq,
                                                      const int* __restrict__ mask,
                                                      const float* __restrict__ Wq,
                                                      const float* __restrict__ Wh,
                                                      const float* __restrict__ Wv,
                                                      const float* __restrict__ Wo,
                                                      float* __restrict__ out) {
  __shared__ float scores[L_ * H_];  // 32 KB, layout [row][h]
  __shared__ int   sidx[H_][K_];
  __shared__ float sw[H_][K_];
  __shared__ float svec[H_][64];
  __shared__ float tvec[H_][16];
  __shared__ float part[H_][64];

  const int b = blockIdx.x;
  const int tid = threadIdx.x;
  const int w = tid >> 6;   // wave id (phase1: interleave slot; later: head id)
  const int ln = tid & 63;
  const int g = ln >> 4;    // row subgroup 0..3
  const int j = ln & 15;    // float4 column index
  const float* __restrict__ seqb = seq + (size_t)b * (L_ * IND_);
  const int* __restrict__ maskb = mask + (size_t)b * L_;
  const bool b1 = (ln & 1) != 0;
  const bool b2 = (ln & 2) != 0;

  // ---------- phase-1 pointers ----------
  // row = s*16 + w*4 + g, col = j  ->  float4 idx = s*256 + w*64 + g*16 + j
  const float4* __restrict__ lp4 =
      reinterpret_cast<const float4*>(seqb) + (w << 6) + (g << 4) + j;
  const int rb0 = (w << 2) + g;  // row base (without s*16 term)

  float4 vvA[8], vvB[8];

#define LOADB(V, SB)                                                          \
  {                                                                           \
    _Pragma("unroll") for (int u = 0; u < 8; ++u)                             \
        V[u] = lp4[(((SB) << 3) + u) << 8];                                   \
  }
#define COMPUTE(V, SB)                                                        \
  {                                                                           \
    _Pragma("unroll") for (int u = 0; u < 8; ++u) {                           \
      const int s = ((SB) << 3) + u;                                          \
      const float4 v = V[u];                                                  \
      float p0 = v.x * wefv[0][0]; p0 = fmaf(v.y, wefv[0][1], p0);            \
      p0 = fmaf(v.z, wefv[0][2], p0); p0 = fmaf(v.w, wefv[0][3], p0);         \
      float p1 = v.x * wefv[1][0]; p1 = fmaf(v.y, wefv[1][1], p1);            \
      p1 = fmaf(v.z, wefv[1][2], p1); p1 = fmaf(v.w, wefv[1][3], p1);         \
      float p2 = v.x * wefv[2][0]; p2 = fmaf(v.y, wefv[2][1], p2);            \
      p2 = fmaf(v.z, wefv[2][2], p2); p2 = fmaf(v.w, wefv[2][3], p2);         \
      float p3 = v.x * wefv[3][0]; p3 = fmaf(v.y, wefv[3][1], p3);            \
      p3 = fmaf(v.z, wefv[3][2], p3); p3 = fmaf(v.w, wefv[3][3], p3);         \
      /* head-interleaved butterfly over the 16-lane group */                 \
      const float a  = (b1 ? p1 : p0) + dpp_f<0xB1>(b1 ? p0 : p1);            \
      const float bb = (b1 ? p3 : p2) + dpp_f<0xB1>(b1 ? p2 : p3);            \
      float c = (b2 ? bb : a) + dpp_f<0x4E>(b2 ? a : bb);                     \
      c += swz_f<0x101F>(c); /* xor 4 */                                      \
      c += swz_f<0x201F>(c); /* xor 8 */                                      \
      const int row = (s << 4) + rb0;                                         \
      if (j < 4) scores[(row << 2) + j] = c;                                  \
    }                                                                         \
  }

  // prologue loads first: 16 KB/wave in flight while weff is computed below
  LOADB(vvA, 0);
  LOADB(vvB, 1);

  // ---------- in-kernel weff (per-wave redundant, f64, barrier-free) -------
  // q[a] = sum_j target[b][j] * Wq[j][a]   (lane a holds q[a])
  // weff[i][h] = (1/4) sum_d q[h*16+d] * Wh[i][h*16+d]  (lane i holds 4 h's)
  float wefv[H_][4];
  {
    const float tgtv = target[b * 64 + ln];
    double qa = 0.0;
#pragma unroll
    for (int jj = 0; jj < 64; ++jj) {
      const double tj = (double)__shfl(tgtv, jj, 64);
      qa = fma(tj, (double)Wq[jj * 64 + ln], qa);
    }
    float wef_i[H_];
#pragma unroll
    for (int h = 0; h < H_; ++h) {
      double a2 = 0.0;
#pragma unroll
      for (int d = 0; d < 16; ++d) {
        const double qv = __shfl(qa, h * 16 + d, 64);
        a2 = fma(qv, (double)Wh[ln * 64 + h * 16 + d], a2);
      }
      wef_i[h] = (float)(a2 * 0.25);  // fold 1/SCALE
    }
    // redistribute: wefv[h][e] = weff[4j+e][h]  (16 shfls)
#pragma unroll
    for (int h = 0; h < H_; ++h)
#pragma unroll
      for (int e = 0; e < 4; ++e)
        wefv[h][e] = __shfl(wef_i[h], (j << 2) + e, 64);
  }

  // ---------- phase 1: scoring, zero barriers, 8-deep pipelined batches ----
                  COMPUTE(vvA, 0);
  LOADB(vvA, 2);  COMPUTE(vvB, 1);
  LOADB(vvB, 3);  COMPUTE(vvA, 2);
  LOADB(vvA, 4);  COMPUTE(vvB, 3);
  LOADB(vvB, 5);  COMPUTE(vvA, 4);
  LOADB(vvA, 6);  COMPUTE(vvB, 5);
  LOADB(vvB, 7);  COMPUTE(vvA, 6);
  LOADB(vvA, 8);  COMPUTE(vvB, 7);
  LOADB(vvB, 9);  COMPUTE(vvA, 8);
  LOADB(vvA, 10); COMPUTE(vvB, 9);
  LOADB(vvB, 11); COMPUTE(vvA, 10);
  LOADB(vvA, 12); COMPUTE(vvB, 11);
  LOADB(vvB, 13); COMPUTE(vvA, 12);
  LOADB(vvA, 14); COMPUTE(vvB, 13);
  LOADB(vvB, 15); COMPUTE(vvA, 14);
                  COMPUTE(vvB, 15);
#undef LOADB
#undef COMPUTE

  // mask bits for this lane's selection rows
  unsigned mbits = 0;
#pragma unroll
  for (int t = 0; t < 32; ++t) mbits |= (maskb[(t << 6) + ln] ? 1u : 0u) << t;

  __syncthreads();  // scoreboard complete; wave w now owns head w

  // ---------- selection: exact 64th-largest via bitwise binary search ------
  unsigned kk[32];
  const unsigned KNEG = f2key(-1e9f);
#pragma unroll
  for (int t = 0; t < 32; ++t) {
    const float s_ = scores[(((t << 6) + ln) << 2) + w];
    kk[t] = ((mbits >> t) & 1u) ? f2key(s_) : KNEG;
  }

  unsigned kmax = 0u;
#pragma unroll
  for (int q = 0; q < 32; ++q) kmax = max(kmax, kk[q]);
#pragma unroll
  for (int off = 32; off >= 1; off >>= 1)
    kmax = max(kmax, (unsigned)__shfl_xor((int)kmax, off, 64));
  const float smax = key2f(kmax);

  unsigned lo = 0u, hi = 0xFFFFFFFFu;
  while (lo < hi) {  // find max t with count(key >= t) >= 64
    const unsigned span = hi - lo;
    const unsigned mid = lo + (span >> 1) + (span & 1u);
    int c = 0;
#pragma unroll
    for (int q = 0; q < 32; ++q) c += (kk[q] >= mid) ? 1 : 0;
#pragma unroll
    for (int off = 32; off >= 1; off >>= 1) c += __shfl_xor(c, off, 64);
    if (c >= K_) lo = mid; else hi = mid - 1;
  }
  const unsigned V = lo;
  int cg = 0;
#pragma unroll
  for (int q = 0; q < 32; ++q) cg += (kk[q] > V) ? 1 : 0;
#pragma unroll
  for (int off = 32; off >= 1; off >>= 1) cg += __shfl_xor(cg, off, 64);
  const int m = K_ - cg;  // #ties (==V) to take, lowest index first (lax.top_k stable)

  {
    const unsigned long long lmlt = (1ull << ln) - 1ull;
    int gbase = 0, etaken = 0;
#pragma unroll
    for (int q = 0; q < 32; ++q) {
      const unsigned key = kk[q];
      const int l = ln + (q << 6);  // lane order == index order within chunk
      const bool gt = key > V;
      const bool eq = key == V;
      const unsigned long long bgt = __ballot(gt);
      const unsigned long long beq = __ballot(eq);
      if (gt) {
        const int pos = gbase + __popcll(bgt & lmlt);
        sidx[w][pos] = l;
        sw[w][pos] = expf(key2f(key) - smax);
      }
      const int navail = __popcll(beq);
      const int take = min(m - etaken, navail);
      if (eq) {
        const int rk = __popcll(beq & lmlt);
        if (rk < take) {
          const int pos = 63 - (etaken + rk);  // ties fill from the back
          sidx[w][pos] = l;
          sw[w][pos] = expf(key2f(key) - smax);
        }
      }
      gbase += __popcll(bgt);
      etaken += take;
    }
  }
  // no barrier: sidx/sw written and read by the same wave

  // ---------- gather + softmax-weighted sum of raw seq rows ----------
  {
    const int cg4 = ln & 15;  // float4 column group
    const int rg = ln >> 4;   // row subgroup 0..3
    float4 sv = make_float4(0.f, 0.f, 0.f, 0.f);
    float z = 0.f;
#pragma unroll
    for (int q = 0; q < 16; ++q) {
      const int sl = (q << 2) + rg;
      const int idx = sidx[w][sl];
      const float wt = sw[w][sl];
      const float4 v =
          *reinterpret_cast<const float4*>(seqb + (size_t)idx * 64 + (cg4 << 2));
      sv.x = fmaf(wt, v.x, sv.x);
      sv.y = fmaf(wt, v.y, sv.y);
      sv.z = fmaf(wt, v.z, sv.z);
      sv.w = fmaf(wt, v.w, sv.w);
      z += wt;
    }
#pragma unroll
    for (int off = 16; off <= 32; off <<= 1) {
      sv.x += __shfl_xor(sv.x, off, 64);
      sv.y += __shfl_xor(sv.y, off, 64);
      sv.z += __shfl_xor(sv.z, off, 64);
      sv.w += __shfl_xor(sv.w, off, 64);
      z += __shfl_xor(z, off, 64);
    }
    if (rg == 0) {  // lanes 0..15 hold the reduced result
      const float inv = 1.f / z;
      svec[w][(cg4 << 2) + 0] = sv.x * inv;
      svec[w][(cg4 << 2) + 1] = sv.y * inv;
      svec[w][(cg4 << 2) + 2] = sv.z * inv;
      svec[w][(cg4 << 2) + 3] = sv.w * inv;
    }
  }
  // svec written and read by the same wave -> no barrier

  // ---------- epilogue (verified): out_h = (svec_h @ Wv_h) @ Wo_h ----------
  {
    // t[d] = sum_i svec[i] * Wv[i][w*16+d]; lane (g,j) does i = 4*i16+g, d=j
    float tp = 0.f;
#pragma unroll
    for (int i16 = 0; i16 < 16; ++i16) {
      const int i = (i16 << 2) + g;
      tp = fmaf(svec[w][i], Wv[i * 64 + (w << 4) + j], tp);
    }
    tp += __shfl_xor(tp, 16, 64);
    tp += __shfl_xor(tp, 32, 64);   // all lanes now hold t[d=j]
    if (ln < 16) tvec[w][ln] = tp;  // lane ln<16 has g==0, d=ln
    float o = 0.f;
#pragma unroll
    for (int d = 0; d < 16; ++d)
      o = fmaf(tvec[w][d], Wo[((w << 4) + d) * 64 + ln], o);
    part[w][ln] = o;
  }
  __syncthreads();
  if (tid < 64)
    out[(size_t)b * 64 + tid] = part[0][tid] + part[1][tid] + part[2][tid] + part[3][tid];
}

extern "C" void kernel_launch(void* const* d_in, const int* in_sizes, int n_in,
                              void* d_out, int out_size, void* d_ws, size_t ws_size,
                              hipStream_t stream) {
  const float* target = (const float*)d_in[0];
  const float* seq    = (const float*)d_in[1];
  const int*   mask   = (const int*)d_in[2];
  const float* Wq     = (const float*)d_in[3];
  const float* Wh     = (const float*)d_in[4];
  const float* Wv     = (const float*)d_in[5];
  const float* Wo     = (const float*)d_in[6];
  float* out = (float*)d_out;
  (void)d_ws; (void)ws_size;

  attn_main_k<<<B_, 256, 0, stream>>>(target, seq, mask, Wq, Wh, Wv, Wo, out);
}

// Round 17
// 115.237 us; speedup vs baseline: 1.2179x; 1.0593x over previous
//
#include <hip/hip_runtime.h>

#define B_   1024
#define L_   2048
#define IND_ 64
#define H_   4
#define K_   64

typedef float f32x4 __attribute__((ext_vector_type(4)));  // native vec for nt-load

// monotone float->uint key (order-preserving), and inverse
__device__ __forceinline__ unsigned f2key(float s) {
  unsigned u = __float_as_uint(s);
  return (u & 0x80000000u) ? ~u : (u | 0x80000000u);
}
__device__ __forceinline__ float key2f(unsigned k) {
  unsigned u = (k & 0x80000000u) ? (k & 0x7FFFFFFFu) : ~k;
  return __uint_as_float(u);
}

// DPP cross-lane move (bound_ctrl=true: invalid -> 0).
// quad_perm 0xB1 = [1,0,3,2] (xor 1); 0x4E = [2,3,0,1] (xor 2).
template <int CTRL>
__device__ __forceinline__ float dpp_f(float x) {
  return __int_as_float(
      __builtin_amdgcn_update_dpp(0, __float_as_int(x), CTRL, 0xf, 0xf, true));
}
// ds_swizzle BitMode xor: offset = (xor<<10) | 0x1F. LDS pipe (offloads VALU).
template <int OFF>
__device__ __forceinline__ float swz_f(float x) {
  return __int_as_float(__builtin_amdgcn_ds_swizzle(__float_as_int(x), OFF));
}

// ---------------- ONE kernel: one block per b; 4 waves ----------------------
// R15 structure (122 us) with ONE change: phase-1 stream loads are
// NONTEMPORAL (read-once data; avoid L1/L2/L3 allocation churn from pushing
// 512 MB through a 256 MB L3). Gather/mask/weights stay cached.
// R16 lesson: __builtin_nontemporal_load needs a NATIVE vector type
// (ext_vector_type), not HIP's float4 struct.
__global__ __launch_bounds__(256, 4) void attn_main_k(const float* __restrict__ target,
                                                      const float* __restrict__ seq,
                                                      const int* __restrict__ mask,
                                                      const float* __restrict__ Wq,
                                                      const float* __restrict__ Wh,
                                                      const float* __restrict__ Wv,
                                                      const float* __restrict__ Wo,
                                                      float* __restrict__ out) {
  __shared__ float scores[L_ * H_];  // 32 KB, layout [row][h]
  __shared__ int   sidx[H_][K_];
  __shared__ float sw[H_][K_];
  __shared__ float svec[H_][64];
  __shared__ float tvec[H_][16];
  __shared__ float part[H_][64];

  const int b = blockIdx.x;
  const int tid = threadIdx.x;
  const int w = tid >> 6;   // wave id (phase1: interleave slot; later: head id)
  const int ln = tid & 63;
  const int g = ln >> 4;    // row subgroup 0..3
  const int j = ln & 15;    // float4 column index
  const float* __restrict__ seqb = seq + (size_t)b * (L_ * IND_);
  const int* __restrict__ maskb = mask + (size_t)b * L_;
  const bool b1 = (ln & 1) != 0;
  const bool b2 = (ln & 2) != 0;

  // ---------- phase-1 pointers ----------
  // row = s*16 + w*4 + g, col = j  ->  float4 idx = s*256 + w*64 + g*16 + j
  const f32x4* __restrict__ lp4 =
      reinterpret_cast<const f32x4*>(seqb) + (w << 6) + (g << 4) + j;
  const int rb0 = (w << 2) + g;  // row base (without s*16 term)

  f32x4 vvA[8], vvB[8];

#define LOADB(V, SB)                                                          \
  {                                                                           \
    _Pragma("unroll") for (int u = 0; u < 8; ++u)                             \
        V[u] = __builtin_nontemporal_load(&lp4[(((SB) << 3) + u) << 8]);      \
  }
#define COMPUTE(V, SB)                                                        \
  {                                                                           \
    _Pragma("unroll") for (int u = 0; u < 8; ++u) {                           \
      const int s = ((SB) << 3) + u;                                          \
      const f32x4 v = V[u];                                                   \
      float p0 = v.x * wefv[0][0]; p0 = fmaf(v.y, wefv[0][1], p0);            \
      p0 = fmaf(v.z, wefv[0][2], p0); p0 = fmaf(v.w, wefv[0][3], p0);         \
      float p1 = v.x * wefv[1][0]; p1 = fmaf(v.y, wefv[1][1], p1);            \
      p1 = fmaf(v.z, wefv[1][2], p1); p1 = fmaf(v.w, wefv[1][3], p1);         \
      float p2 = v.x * wefv[2][0]; p2 = fmaf(v.y, wefv[2][1], p2);            \
      p2 = fmaf(v.z, wefv[2][2], p2); p2 = fmaf(v.w, wefv[2][3], p2);         \
      float p3 = v.x * wefv[3][0]; p3 = fmaf(v.y, wefv[3][1], p3);            \
      p3 = fmaf(v.z, wefv[3][2], p3); p3 = fmaf(v.w, wefv[3][3], p3);         \
      /* head-interleaved butterfly over the 16-lane group */                 \
      const float a  = (b1 ? p1 : p0) + dpp_f<0xB1>(b1 ? p0 : p1);            \
      const float bb = (b1 ? p3 : p2) + dpp_f<0xB1>(b1 ? p2 : p3);            \
      float c = (b2 ? bb : a) + dpp_f<0x4E>(b2 ? a : bb);                     \
      c += swz_f<0x101F>(c); /* xor 4 */                                      \
      c += swz_f<0x201F>(c); /* xor 8 */                                      \
      const int row = (s << 4) + rb0;                                         \
      if (j < 4) scores[(row << 2) + j] = c;                                  \
    }                                                                         \
  }

  // prologue loads first: 16 KB/wave in flight while weff is computed below
  LOADB(vvA, 0);
  LOADB(vvB, 1);

  // ---------- in-kernel weff (per-wave redundant, f64, barrier-free) -------
  float wefv[H_][4];
  {
    const float tgtv = target[b * 64 + ln];
    double qa = 0.0;
#pragma unroll
    for (int jj = 0; jj < 64; ++jj) {
      const double tj = (double)__shfl(tgtv, jj, 64);
      qa = fma(tj, (double)Wq[jj * 64 + ln], qa);
    }
    float wef_i[H_];
#pragma unroll
    for (int h = 0; h < H_; ++h) {
      double a2 = 0.0;
#pragma unroll
      for (int d = 0; d < 16; ++d) {
        const double qv = __shfl(qa, h * 16 + d, 64);
        a2 = fma(qv, (double)Wh[ln * 64 + h * 16 + d], a2);
      }
      wef_i[h] = (float)(a2 * 0.25);  // fold 1/SCALE
    }
#pragma unroll
    for (int h = 0; h < H_; ++h)
#pragma unroll
      for (int e = 0; e < 4; ++e)
        wefv[h][e] = __shfl(wef_i[h], (j << 2) + e, 64);
  }

  // ---------- phase 1: scoring, zero barriers, 8-deep pipelined batches ----
                  COMPUTE(vvA, 0);
  LOADB(vvA, 2);  COMPUTE(vvB, 1);
  LOADB(vvB, 3);  COMPUTE(vvA, 2);
  LOADB(vvA, 4);  COMPUTE(vvB, 3);
  LOADB(vvB, 5);  COMPUTE(vvA, 4);
  LOADB(vvA, 6);  COMPUTE(vvB, 5);
  LOADB(vvB, 7);  COMPUTE(vvA, 6);
  LOADB(vvA, 8);  COMPUTE(vvB, 7);
  LOADB(vvB, 9);  COMPUTE(vvA, 8);
  LOADB(vvA, 10); COMPUTE(vvB, 9);
  LOADB(vvB, 11); COMPUTE(vvA, 10);
  LOADB(vvA, 12); COMPUTE(vvB, 11);
  LOADB(vvB, 13); COMPUTE(vvA, 12);
  LOADB(vvA, 14); COMPUTE(vvB, 13);
  LOADB(vvB, 15); COMPUTE(vvA, 14);
                  COMPUTE(vvB, 15);
#undef LOADB
#undef COMPUTE

  // mask bits for this lane's selection rows
  unsigned mbits = 0;
#pragma unroll
  for (int t = 0; t < 32; ++t) mbits |= (maskb[(t << 6) + ln] ? 1u : 0u) << t;

  __syncthreads();  // scoreboard complete; wave w now owns head w

  // ---------- selection: exact 64th-largest via bitwise binary search ------
  unsigned kk[32];
  const unsigned KNEG = f2key(-1e9f);
#pragma unroll
  for (int t = 0; t < 32; ++t) {
    const float s_ = scores[(((t << 6) + ln) << 2) + w];
    kk[t] = ((mbits >> t) & 1u) ? f2key(s_) : KNEG;
  }

  unsigned kmax = 0u;
#pragma unroll
  for (int q = 0; q < 32; ++q) kmax = max(kmax, kk[q]);
#pragma unroll
  for (int off = 32; off >= 1; off >>= 1)
    kmax = max(kmax, (unsigned)__shfl_xor((int)kmax, off, 64));
  const float smax = key2f(kmax);

  unsigned lo = 0u, hi = 0xFFFFFFFFu;
  while (lo < hi) {  // find max t with count(key >= t) >= 64
    const unsigned span = hi - lo;
    const unsigned mid = lo + (span >> 1) + (span & 1u);
    int c = 0;
#pragma unroll
    for (int q = 0; q < 32; ++q) c += (kk[q] >= mid) ? 1 : 0;
#pragma unroll
    for (int off = 32; off >= 1; off >>= 1) c += __shfl_xor(c, off, 64);
    if (c >= K_) lo = mid; else hi = mid - 1;
  }
  const unsigned V = lo;
  int cg = 0;
#pragma unroll
  for (int q = 0; q < 32; ++q) cg += (kk[q] > V) ? 1 : 0;
#pragma unroll
  for (int off = 32; off >= 1; off >>= 1) cg += __shfl_xor(cg, off, 64);
  const int m = K_ - cg;  // #ties (==V) to take, lowest index first (lax.top_k stable)

  {
    const unsigned long long lmlt = (1ull << ln) - 1ull;
    int gbase = 0, etaken = 0;
#pragma unroll
    for (int q = 0; q < 32; ++q) {
      const unsigned key = kk[q];
      const int l = ln + (q << 6);  // lane order == index order within chunk
      const bool gt = key > V;
      const bool eq = key == V;
      const unsigned long long bgt = __ballot(gt);
      const unsigned long long beq = __ballot(eq);
      if (gt) {
        const int pos = gbase + __popcll(bgt & lmlt);
        sidx[w][pos] = l;
        sw[w][pos] = expf(key2f(key) - smax);
      }
      const int navail = __popcll(beq);
      const int take = min(m - etaken, navail);
      if (eq) {
        const int rk = __popcll(beq & lmlt);
        if (rk < take) {
          const int pos = 63 - (etaken + rk);  // ties fill from the back
          sidx[w][pos] = l;
          sw[w][pos] = expf(key2f(key) - smax);
        }
      }
      gbase += __popcll(bgt);
      etaken += take;
    }
  }
  // no barrier: sidx/sw written and read by the same wave

  // ---------- gather + softmax-weighted sum of raw seq rows (cached) -------
  {
    const int cg4 = ln & 15;  // float4 column group
    const int rg = ln >> 4;   // row subgroup 0..3
    float4 sv = make_float4(0.f, 0.f, 0.f, 0.f);
    float z = 0.f;
#pragma unroll
    for (int q = 0; q < 16; ++q) {
      const int sl = (q << 2) + rg;
      const int idx = sidx[w][sl];
      const float wt = sw[w][sl];
      const float4 v =
          *reinterpret_cast<const float4*>(seqb + (size_t)idx * 64 + (cg4 << 2));
      sv.x = fmaf(wt, v.x, sv.x);
      sv.y = fmaf(wt, v.y, sv.y);
      sv.z = fmaf(wt, v.z, sv.z);
      sv.w = fmaf(wt, v.w, sv.w);
      z += wt;
    }
#pragma unroll
    for (int off = 16; off <= 32; off <<= 1) {
      sv.x += __shfl_xor(sv.x, off, 64);
      sv.y += __shfl_xor(sv.y, off, 64);
      sv.z += __shfl_xor(sv.z, off, 64);
      sv.w += __shfl_xor(sv.w, off, 64);
      z += __shfl_xor(z, off, 64);
    }
    if (rg == 0) {  // lanes 0..15 hold the reduced result
      const float inv = 1.f / z;
      svec[w][(cg4 << 2) + 0] = sv.x * inv;
      svec[w][(cg4 << 2) + 1] = sv.y * inv;
      svec[w][(cg4 << 2) + 2] = sv.z * inv;
      svec[w][(cg4 << 2) + 3] = sv.w * inv;
    }
  }
  // svec written and read by the same wave -> no barrier

  // ---------- epilogue (verified): out_h = (svec_h @ Wv_h) @ Wo_h ----------
  {
    float tp = 0.f;
#pragma unroll
    for (int i16 = 0; i16 < 16; ++i16) {
      const int i = (i16 << 2) + g;
      tp = fmaf(svec[w][i], Wv[i * 64 + (w << 4) + j], tp);
    }
    tp += __shfl_xor(tp, 16, 64);
    tp += __shfl_xor(tp, 32, 64);   // all lanes now hold t[d=j]
    if (ln < 16) tvec[w][ln] = tp;  // lane ln<16 has g==0, d=ln
    float o = 0.f;
#pragma unroll
    for (int d = 0; d < 16; ++d)
      o = fmaf(tvec[w][d], Wo[((w << 4) + d) * 64 + ln], o);
    part[w][ln] = o;
  }
  __syncthreads();
  if (tid < 64)
    out[(size_t)b * 64 + tid] = part[0][tid] + part[1][tid] + part[2][tid] + part[3][tid];
}

extern "C" void kernel_launch(void* const* d_in, const int* in_sizes, int n_in,
                              void* d_out, int out_size, void* d_ws, size_t ws_size,
                              hipStream_t stream) {
  const float* target = (const float*)d_in[0];
  const float* seq    = (const float*)d_in[1];
  const int*   mask   = (const int*)d_in[2];
  const float* Wq     = (const float*)d_in[3];
  const float* Wh     = (const float*)d_in[4];
  const float* Wv     = (const float*)d_in[5];
  const float* Wo     = (const float*)d_in[6];
  float* out = (float*)d_out;
  (void)d_ws; (void)ws_size;

  attn_main_k<<<B_, 256, 0, stream>>>(target, seq, mask, Wq, Wh, Wv, Wo, out);
}